// Round 1
// baseline (5180.316 us; speedup 1.0000x reference)
//
#include <hip/hip_runtime.h>
#include <math.h>

#define SELU_ALPHA 1.6732632423543772f
#define SELU_SCALE 1.0507009873554805f

__device__ __forceinline__ float selu_f(float x) {
    return x > 0.f ? SELU_SCALE * x : SELU_SCALE * SELU_ALPHA * (expf(x) - 1.f);
}

constexpr int Bb = 256, Ll = 100, Hh = 1000, Ee = 100, Rr = 247, Tt = 15;
constexpr int NC = 3456;        // packed weight cols: [W_hh(3000) | W_pred(247) | W_eos(1) | pad(80) | W_fuse_top(100) | pad(28)]
constexpr int N_PRED0 = 3000;
constexpr int N_EOS   = 3247;
constexpr int N_FUSE0 = 3328;
constexpr int OUTW = Rr + 1 + Ll + 1;  // 349

// ---------------- attention: scores -> softmax -> context (per batch) -------
__global__ void attn_ctx_kernel(const float* __restrict__ mem, const float* __restrict__ Wb,
                                float* __restrict__ ctx, int Nmem) {
    __shared__ float s_a[256];
    __shared__ float s_red[256];
    int b = blockIdx.x;
    int tid = threadIdx.x, lane = tid & 63, wave = tid >> 6;
    const float* memb = mem + (size_t)b * Nmem * Hh;
    // scores (softmax is invariant to the h-term and b_attn, so skip them)
    for (int l = wave; l < Nmem; l += 4) {
        const float* row = memb + (size_t)l * Hh;
        float p = 0.f;
        for (int k = lane; k < Hh; k += 64) p += row[k] * Wb[k];
        for (int off = 32; off > 0; off >>= 1) p += __shfl_down(p, off);
        if (lane == 0) s_a[l] = p;
    }
    __syncthreads();
    float m = -1e30f;
    for (int l = tid; l < Nmem; l += 256) m = fmaxf(m, s_a[l]);
    s_red[tid] = m; __syncthreads();
    for (int s = 128; s > 0; s >>= 1) { if (tid < s) s_red[tid] = fmaxf(s_red[tid], s_red[tid+s]); __syncthreads(); }
    m = s_red[0]; __syncthreads();
    float psum = 0.f;
    for (int l = tid; l < Nmem; l += 256) { float e = expf(s_a[l] - m); s_a[l] = e; psum += e; }
    s_red[tid] = psum; __syncthreads();
    for (int s = 128; s > 0; s >>= 1) { if (tid < s) s_red[tid] += s_red[tid+s]; __syncthreads(); }
    float inv = 1.f / s_red[0];
    __syncthreads();
    for (int l = tid; l < Nmem; l += 256) s_a[l] *= inv;
    __syncthreads();
    for (int h = tid; h < Hh; h += 256) {
        float acc = 0.f;
        for (int l = 0; l < Nmem; ++l) acc += s_a[l] * memb[(size_t)l*Hh + h];
        ctx[(size_t)b*Hh + h] = acc;
    }
}

// ------------- xc = c@W_comb[E:] + b_comb ; xrc likewise ---------------------
__global__ void xcxrc_kernel(const float* __restrict__ c, const float* __restrict__ rc,
                             const float* __restrict__ W_comb, const float* __restrict__ b_comb,
                             float* __restrict__ xc, float* __restrict__ xrc) {
    __shared__ float sc[1000];
    __shared__ float sr[1000];
    int b = blockIdx.x, tid = threadIdx.x;  // 128 threads
    for (int k = tid; k < Hh; k += 128) { sc[k] = c[(size_t)b*Hh+k]; sr[k] = rc[(size_t)b*Hh+k]; }
    __syncthreads();
    if (tid < Ee) {
        float a0 = 0.f, a1 = 0.f;
        for (int k = 0; k < Hh; ++k) {
            float w = W_comb[(size_t)(Ee + k)*Ee + tid];
            a0 += sc[k]*w; a1 += sr[k]*w;
        }
        xc [(size_t)b*Ee + tid] = a0 + b_comb[tid];
        xrc[(size_t)b*Ee + tid] = a1 + b_comb[tid];
    }
}

// ------------- x_all[t][b] = emb[b,t]@W_comb[:E] + (t%3==0?xrc:xc)[b] --------
__global__ void xall_kernel(const float* __restrict__ emb, const float* __restrict__ W_comb,
                            const float* __restrict__ xc, const float* __restrict__ xrc,
                            float* __restrict__ x_all) {
    __shared__ float se[100];
    int bt = blockIdx.x; int b = bt / Tt, t = bt % Tt;
    int tid = threadIdx.x;  // 128
    if (tid < Ee) se[tid] = emb[(size_t)(b*Tt + t)*Ee + tid];
    __syncthreads();
    if (tid < Ee) {
        float a = 0.f;
        for (int k = 0; k < Ee; ++k) a += se[k] * W_comb[(size_t)k*Ee + tid];
        const float* xs = (t % 3 == 0) ? xrc : xc;
        x_all[((size_t)t*Bb + b)*Ee + tid] = a + xs[(size_t)b*Ee + tid];
    }
}

// ------------- pack [W_hh | W_pred | W_eos | 0 | W_fuse_top | 0] -------------
__global__ void pack_wcat(const float* __restrict__ W_hh, const float* __restrict__ W_pred,
                          const float* __restrict__ W_eos, const float* __restrict__ W_fuse,
                          float* __restrict__ Wcat) {
    int k = blockIdx.x;  // 0..999
    for (int n = threadIdx.x; n < NC; n += blockDim.x) {
        float v;
        if      (n < N_PRED0) v = W_hh[(size_t)k*3000 + n];
        else if (n < N_EOS)   v = W_pred[(size_t)k*Rr + (n - N_PRED0)];
        else if (n == N_EOS)  v = W_eos[k];
        else if (n < N_FUSE0) v = 0.f;
        else if (n < N_FUSE0 + 100) v = W_fuse[(size_t)k*100 + (n - N_FUSE0)];
        else v = 0.f;
        Wcat[(size_t)k*NC + n] = v;
    }
}
__global__ void pack_bcat(const float* __restrict__ b_hh, const float* __restrict__ b_pred,
                          const float* __restrict__ b_eos, float* __restrict__ bcat) {
    int n = blockIdx.x*256 + threadIdx.x;
    if (n >= NC) return;
    float v;
    if      (n < N_PRED0) v = b_hh[n];
    else if (n < N_EOS)   v = b_pred[n - N_PRED0];
    else if (n == N_EOS)  v = b_eos[0];
    else v = 0.f;
    bcat[n] = v;
}

// ------------- generic fp32 tiled GEMM: C = act(A) @ B (+bias) ---------------
// MODE 0: plain. MODE 1: selu(A). MODE 2: selu(A) only for n-blocks >= nSeluStart.
template<int BM, int BN, int BK, int TM, int TN, int MODE>
__launch_bounds__(256)
__global__ void gemm_k(const float* __restrict__ A, const float* __restrict__ Bm,
                       const float* __restrict__ bias, float* __restrict__ C,
                       int M, int N, int K, int nSeluStart) {
    __shared__ float As[BK][BM + 4];
    __shared__ float Bs[BK][BN];
    constexpr int TX = BN / TN;  // 16
    int tid = threadIdx.x;
    int tx = tid % TX, ty = tid / TX;
    int n0 = blockIdx.x * BN, m0 = blockIdx.y * BM;
    bool use_selu = (MODE == 1) || (MODE == 2 && n0 >= nSeluStart);
    float acc[TM][TN];
    #pragma unroll
    for (int i = 0; i < TM; i++)
        #pragma unroll
        for (int j = 0; j < TN; j++) acc[i][j] = 0.f;

    for (int k0 = 0; k0 < K; k0 += BK) {
        constexpr int A_ELEMS = BM*BK/256;
        #pragma unroll
        for (int e = 0; e < A_ELEMS; ++e) {
            int idx = tid + e*256;
            int mi = idx / BK, kk = idx % BK;
            int mm = m0 + mi, kg = k0 + kk;
            float v = (mm < M && kg < K) ? A[(size_t)mm*K + kg] : 0.f;
            if (use_selu) v = selu_f(v);
            As[kk][mi] = v;
        }
        constexpr int B_ELEMS = BK*BN/256;
        #pragma unroll
        for (int e = 0; e < B_ELEMS; ++e) {
            int idx = tid + e*256;
            int kk = idx / BN, nn = idx % BN;
            int kg = k0 + kk, ng = n0 + nn;
            Bs[kk][nn] = (kg < K && ng < N) ? Bm[(size_t)kg*N + ng] : 0.f;
        }
        __syncthreads();
        #pragma unroll
        for (int kk = 0; kk < BK; ++kk) {
            float ra[TM], rb[TN];
            #pragma unroll
            for (int i = 0; i < TM; i++) ra[i] = As[kk][ty*TM + i];
            #pragma unroll
            for (int j = 0; j < TN; j++) rb[j] = Bs[kk][tx*TN + j];
            #pragma unroll
            for (int i = 0; i < TM; i++)
                #pragma unroll
                for (int j = 0; j < TN; j++)
                    acc[i][j] = fmaf(ra[i], rb[j], acc[i][j]);
        }
        __syncthreads();
    }
    #pragma unroll
    for (int i = 0; i < TM; i++) {
        int mm = m0 + ty*TM + i;
        if (mm >= M) continue;
        #pragma unroll
        for (int j = 0; j < TN; j++) {
            int nn = n0 + tx*TN + j;
            if (nn < N) C[(size_t)mm*N + nn] = acc[i][j] + (bias ? bias[nn] : 0.f);
        }
    }
}

// ------------- GRU gates (elementwise) ---------------------------------------
__global__ void gates_kernel(const float* __restrict__ gi, const float* __restrict__ hg,
                             const float* __restrict__ h_prev, float* __restrict__ h_next) {
    int idx = blockIdx.x*256 + threadIdx.x;
    if (idx >= Bb*Hh) return;
    int b = idx / Hh, j = idx % Hh;
    const float* gib = gi + (size_t)b*3000;
    const float* ghb = hg + (size_t)b*NC;
    float r = 1.f/(1.f + expf(-(gib[j]        + ghb[j])));
    float z = 1.f/(1.f + expf(-(gib[1000 + j] + ghb[1000 + j])));
    float n = tanhf(gib[2000 + j] + r*ghb[2000 + j]);
    h_next[idx] = (1.f - z)*n + z*h_prev[idx];
}

// ------------- per-step outputs: cp + 2x log_softmax -------------------------
__global__ void output_kernel(const float* __restrict__ hg, const float* __restrict__ enc_fuse,
                              const float* __restrict__ b_fuse, const float* __restrict__ W_copy,
                              const float* __restrict__ b_copy, float* __restrict__ out_t) {
    __shared__ float sf[100];
    __shared__ float swc[100];
    __shared__ float scp[101];
    __shared__ float spred[248];
    __shared__ float sred[256];
    int b = blockIdx.x, tid = threadIdx.x, lane = tid & 63, wave = tid >> 6;
    const float* hgb = hg + (size_t)b*NC;
    if (tid < 100) { sf[tid] = hgb[N_FUSE0 + tid] + b_fuse[tid]; swc[tid] = W_copy[tid]; }
    float eos = hgb[N_EOS];
    if (tid < Rr) spred[tid] = hgb[N_PRED0 + tid];
    if (tid == Rr) spred[Rr] = eos;
    if (tid == 0) scp[100] = eos;
    __syncthreads();
    const float* efb = enc_fuse + (size_t)b*Ll*100;
    for (int l = wave; l < Ll; l += 4) {
        const float* ef = efb + (size_t)l*100;
        float p = selu_f(sf[lane] + ef[lane]) * swc[lane];
        if (lane < 36) p += selu_f(sf[lane+64] + ef[lane+64]) * swc[lane+64];
        for (int off = 32; off > 0; off >>= 1) p += __shfl_down(p, off);
        if (lane == 0) scp[l] = p + b_copy[0];
    }
    __syncthreads();
    float* ob = out_t + (size_t)b*OUTW;
    // log_softmax over pred (248)
    float m = -1e30f;
    for (int i = tid; i < 248; i += 256) m = fmaxf(m, spred[i]);
    sred[tid] = m; __syncthreads();
    for (int s = 128; s > 0; s >>= 1) { if (tid < s) sred[tid] = fmaxf(sred[tid], sred[tid+s]); __syncthreads(); }
    m = sred[0]; __syncthreads();
    float ps = 0.f;
    for (int i = tid; i < 248; i += 256) ps += expf(spred[i] - m);
    sred[tid] = ps; __syncthreads();
    for (int s = 128; s > 0; s >>= 1) { if (tid < s) sred[tid] += sred[tid+s]; __syncthreads(); }
    float lse = m + logf(sred[0]);
    __syncthreads();
    for (int i = tid; i < 248; i += 256) ob[i] = spred[i] - lse;
    // log_softmax over copy (101)
    m = -1e30f;
    for (int i = tid; i < 101; i += 256) m = fmaxf(m, scp[i]);
    sred[tid] = m; __syncthreads();
    for (int s = 128; s > 0; s >>= 1) { if (tid < s) sred[tid] = fmaxf(sred[tid], sred[tid+s]); __syncthreads(); }
    m = sred[0]; __syncthreads();
    ps = 0.f;
    for (int i = tid; i < 101; i += 256) ps += expf(scp[i] - m);
    sred[tid] = ps; __syncthreads();
    for (int s = 128; s > 0; s >>= 1) { if (tid < s) sred[tid] += sred[tid+s]; __syncthreads(); }
    lse = m + logf(sred[0]);
    __syncthreads();
    for (int i = tid; i < 101; i += 256) ob[248 + i] = scp[i] - lse;
}

extern "C" void kernel_launch(void* const* d_in, const int* in_sizes, int n_in,
                              void* d_out, int out_size, void* d_ws, size_t ws_size,
                              hipStream_t stream) {
    const float* emb    = (const float*)d_in[0];
    const float* enc    = (const float*)d_in[1];
    const float* conv   = (const float*)d_in[2];
    const float* h0     = (const float*)d_in[3];
    const float* W_attn = (const float*)d_in[4];
    const float* W_comb = (const float*)d_in[6];
    const float* b_comb = (const float*)d_in[7];
    const float* W_ih   = (const float*)d_in[8];
    const float* W_hh   = (const float*)d_in[9];
    const float* b_ih   = (const float*)d_in[10];
    const float* b_hh   = (const float*)d_in[11];
    const float* W_eos  = (const float*)d_in[12];
    const float* b_eos  = (const float*)d_in[13];
    const float* W_pred = (const float*)d_in[14];
    const float* b_pred = (const float*)d_in[15];
    const float* W_fuse = (const float*)d_in[16];
    const float* b_fuse = (const float*)d_in[17];
    const float* W_copy = (const float*)d_in[18];
    const float* b_copy = (const float*)d_in[19];
    float* out = (float*)d_out;

    float* ws = (float*)d_ws;
    float* c_buf  = ws;  ws += Bb*Hh;
    float* rc_buf = ws;  ws += Bb*Hh;
    float* xc     = ws;  ws += Bb*Ee;
    float* xrc    = ws;  ws += Bb*Ee;
    float* x_all  = ws;  ws += (size_t)Tt*Bb*Ee;
    float* gi_all = ws;  ws += (size_t)Tt*Bb*3000;
    float* encf   = ws;  ws += (size_t)Bb*Ll*100;
    float* Wcat   = ws;  ws += (size_t)Hh*NC;
    float* bcat   = ws;  ws += NC;
    float* hg     = ws;  ws += (size_t)Bb*NC;
    float* h1     = ws;  ws += Bb*Hh;
    float* h2     = ws;  ws += Bb*Hh;

    // ---- precompute (time-invariant attention contexts + folded linears) ----
    attn_ctx_kernel<<<Bb, 256, 0, stream>>>(enc,  W_attn + Hh, c_buf,  Ll);
    attn_ctx_kernel<<<Bb, 256, 0, stream>>>(conv, W_attn + Hh, rc_buf, Rr);
    xcxrc_kernel<<<Bb, 128, 0, stream>>>(c_buf, rc_buf, W_comb, b_comb, xc, xrc);
    xall_kernel<<<Bb*Tt, 128, 0, stream>>>(emb, W_comb, xc, xrc, x_all);
    pack_wcat<<<Hh, 256, 0, stream>>>(W_hh, W_pred, W_eos, W_fuse, Wcat);
    pack_bcat<<<(NC + 255)/256, 256, 0, stream>>>(b_hh, b_pred, b_eos, bcat);
    {   // gi_all = x_all @ W_ih + b_ih : [3840,100]@[100,3000]
        dim3 g((3000 + 127)/128, (Tt*Bb + 63)/64);
        gemm_k<64,128,16,4,8,0><<<g, 256, 0, stream>>>(x_all, W_ih, b_ih, gi_all, Tt*Bb, 3000, Ee, 0);
    }
    {   // enc_fuse = selu(enc) @ W_fuse[H:] : [25600,1000]@[1000,100]
        dim3 g(1, (Bb*Ll + 63)/64);
        gemm_k<64,128,16,4,8,1><<<g, 256, 0, stream>>>(enc, W_fuse + (size_t)Hh*100, nullptr, encf, Bb*Ll, 100, Hh, 0);
    }

    // ---- sequential decode ----
    dim3 gs((NC + 127)/128, (Bb + 31)/32);
    gemm_k<32,128,16,2,8,2><<<gs, 256, 0, stream>>>(h0, Wcat, bcat, hg, Bb, NC, Hh, N_FUSE0);
    const float* hc = h0;
    float* hn = h1;
    for (int t = 0; t < Tt; ++t) {
        gates_kernel<<<(Bb*Hh + 255)/256, 256, 0, stream>>>(gi_all + (size_t)t*Bb*3000, hg, hc, hn);
        gemm_k<32,128,16,2,8,2><<<gs, 256, 0, stream>>>(hn, Wcat, bcat, hg, Bb, NC, Hh, N_FUSE0);
        output_kernel<<<Bb, 256, 0, stream>>>(hg, encf, b_fuse, W_copy, b_copy, out + (size_t)t*Bb*OUTW);
        hc = hn; hn = (hn == h1) ? h2 : h1;
    }
}

// Round 2
// 768.736 us; speedup vs baseline: 6.7387x; 6.7387x over previous
//
#include <hip/hip_runtime.h>
#include <hip/hip_bf16.h>
#include <math.h>

#define SELU_ALPHA 1.6732632423543772f
#define SELU_SCALE 1.0507009873554805f

typedef __attribute__((ext_vector_type(8))) short bf16x8;
typedef __attribute__((ext_vector_type(4))) float f32x4;

__device__ __forceinline__ float selu_f(float x) {
    return x > 0.f ? SELU_SCALE * x : SELU_SCALE * SELU_ALPHA * (__expf(x) - 1.f);
}
__device__ __forceinline__ unsigned short f2bf(float f) {
    __hip_bfloat16 h = __float2bfloat16(f);
    return *(unsigned short*)&h;
}
__device__ __forceinline__ float bf2f(unsigned short u) {
    unsigned int x = ((unsigned int)u) << 16;
    float f; __builtin_memcpy(&f, &x, 4); return f;
}

constexpr int Bb = 256, Ll = 100, Hh = 1000, Ee = 100, Rr = 247, Tt = 15;
constexpr int KP_G = 1024;       // padded K for all bf16 GEMMs
constexpr int OUTW = Rr + 1 + Ll + 1;  // 349

// ================= attention (time-invariant: h-term is a softmax shift) ====
__global__ void scores_kernel(const float* __restrict__ mem, const float* __restrict__ Wb,
                              float* __restrict__ s, int totalRows) {
    __shared__ float4 sW[250];
    int tid = threadIdx.x, lane = tid & 63, wave = tid >> 6;
    for (int i = tid; i < 250; i += 256) sW[i] = ((const float4*)Wb)[i];
    __syncthreads();
    int r0 = blockIdx.x * 16;
    for (int rr = wave; rr < 16; rr += 4) {
        int row = r0 + rr;
        if (row >= totalRows) continue;
        const float4* m4 = (const float4*)(mem + (size_t)row * 1000);
        float acc = 0.f;
        #pragma unroll
        for (int it = 0; it < 4; ++it) {
            int k4 = lane + it * 64;
            if (k4 < 250) {
                float4 a = m4[k4], w = sW[k4];
                acc += a.x*w.x + a.y*w.y + a.z*w.z + a.w*w.w;
            }
        }
        for (int off = 32; off > 0; off >>= 1) acc += __shfl_down(acc, off);
        if (lane == 0) s[row] = acc;
    }
}

__global__ void softmax_kernel(float* __restrict__ s, int Nmem) {  // Nmem <= 256, in-place
    __shared__ float sred[256];
    int b = blockIdx.x, tid = threadIdx.x;
    float* sb = s + (size_t)b * Nmem;
    float v = (tid < Nmem) ? sb[tid] : -1e30f;
    sred[tid] = v; __syncthreads();
    for (int st = 128; st > 0; st >>= 1) { if (tid < st) sred[tid] = fmaxf(sred[tid], sred[tid+st]); __syncthreads(); }
    float m = sred[0]; __syncthreads();
    float e = (tid < Nmem) ? expf(v - m) : 0.f;
    sred[tid] = e; __syncthreads();
    for (int st = 128; st > 0; st >>= 1) { if (tid < st) sred[tid] += sred[tid+st]; __syncthreads(); }
    float inv = 1.f / sred[0];
    if (tid < Nmem) sb[tid] = e * inv;
}

__global__ void ctx_kernel(const float* __restrict__ mem, const float* __restrict__ a,
                           float* __restrict__ ctx, int Nmem) {
    __shared__ float sa[256];
    int b = blockIdx.x, tid = threadIdx.x;
    int h = blockIdx.y * 256 + tid;
    if (tid < Nmem) sa[tid] = a[(size_t)b * Nmem + tid];
    __syncthreads();
    if (h >= Hh) return;
    const float* mb = mem + (size_t)b * Nmem * Hh + h;
    float a0 = 0.f, a1 = 0.f, a2 = 0.f, a3 = 0.f;
    int l = 0;
    for (; l + 3 < Nmem; l += 4) {
        a0 += sa[l]   * mb[(size_t)l * Hh];
        a1 += sa[l+1] * mb[(size_t)(l+1) * Hh];
        a2 += sa[l+2] * mb[(size_t)(l+2) * Hh];
        a3 += sa[l+3] * mb[(size_t)(l+3) * Hh];
    }
    for (; l < Nmem; ++l) a0 += sa[l] * mb[(size_t)l * Hh];
    ctx[(size_t)b * Hh + h] = a0 + a1 + a2 + a3;
}

// ================= small precompute kernels =================================
__global__ void xcxrc_kernel(const float* __restrict__ c, const float* __restrict__ rc,
                             const float* __restrict__ W_comb, const float* __restrict__ b_comb,
                             float* __restrict__ xc, float* __restrict__ xrc) {
    __shared__ float sc[1000];
    __shared__ float sr[1000];
    int b = blockIdx.x, tid = threadIdx.x;  // 128 threads
    for (int k = tid; k < Hh; k += 128) { sc[k] = c[(size_t)b*Hh+k]; sr[k] = rc[(size_t)b*Hh+k]; }
    __syncthreads();
    if (tid < Ee) {
        float a0 = 0.f, a1 = 0.f;
        for (int k = 0; k < Hh; ++k) {
            float w = W_comb[(size_t)(Ee + k)*Ee + tid];
            a0 += sc[k]*w; a1 += sr[k]*w;
        }
        xc [(size_t)b*Ee + tid] = a0 + b_comb[tid];
        xrc[(size_t)b*Ee + tid] = a1 + b_comb[tid];
    }
}

__global__ void xall_kernel(const float* __restrict__ emb, const float* __restrict__ W_comb,
                            const float* __restrict__ xc, const float* __restrict__ xrc,
                            float* __restrict__ x_all) {
    __shared__ float se[100];
    int bt = blockIdx.x; int b = bt / Tt, t = bt % Tt;
    int tid = threadIdx.x;  // 128
    if (tid < Ee) se[tid] = emb[(size_t)(b*Tt + t)*Ee + tid];
    __syncthreads();
    if (tid < Ee) {
        float a = 0.f;
        for (int k = 0; k < Ee; ++k) a += se[k] * W_comb[(size_t)k*Ee + tid];
        const float* xs = (t % 3 == 0) ? xrc : xc;
        x_all[((size_t)t*Bb + b)*Ee + tid] = a + xs[(size_t)b*Ee + tid];
    }
}

// transpose+convert: dst[n][k] (ld 1024) = bf16(src[(row0+k)*srcLd + n]), zero-padded
__global__ void transpose_cvt(const float* __restrict__ src, int srcLd, int kValid, int nValid,
                              int row0, unsigned short* __restrict__ dst, int nRows) {
    __shared__ float tile[32][33];
    int k0 = blockIdx.x * 32, n0 = blockIdx.y * 32;
    int tx = threadIdx.x, ty = threadIdx.y;  // 32 x 8
    for (int i = ty; i < 32; i += 8) {
        int k = k0 + i, n = n0 + tx;
        tile[i][tx] = (k < kValid && n < nValid) ? src[(size_t)(row0 + k)*srcLd + n] : 0.f;
    }
    __syncthreads();
    for (int i = ty; i < 32; i += 8) {
        int n = n0 + i, k = k0 + tx;
        if (n < nRows) dst[(size_t)n*KP_G + k] = f2bf(tile[tx][i]);
    }
}

__global__ void fill_eos_row(const float* __restrict__ W_eos, unsigned short* __restrict__ Whead) {
    int k = blockIdx.x*256 + threadIdx.x;
    if (k < KP_G) Whead[(size_t)247*KP_G + k] = f2bf(k < Hh ? W_eos[k] : 0.f);
}

__global__ void pack_biases(const float* __restrict__ b_hh, const float* __restrict__ b_pred,
                            const float* __restrict__ b_eos, float* __restrict__ bcat,
                            float* __restrict__ bias_pe) {
    int i = blockIdx.x*256 + threadIdx.x;
    if (i < 3072) bcat[i] = (i < 3000) ? b_hh[i] : 0.f;
    if (i < 256) bias_pe[i] = (i < 247) ? b_pred[i] : (i == 247 ? b_eos[0] : 0.f);
}

__global__ void cvt_h0(const float* __restrict__ h0, unsigned short* __restrict__ h0b) {
    int i = blockIdx.x*256 + threadIdx.x;  // 256*1024
    int b = i >> 10, j = i & 1023;
    h0b[i] = f2bf(j < Hh ? h0[(size_t)b*Hh + j] : 0.f);
}

// ================= fp32 GEMM (only for gi_all: K=100) ========================
template<int BM, int BN, int BK, int TM, int TN>
__launch_bounds__(256)
__global__ void gemm_f32(const float* __restrict__ A, const float* __restrict__ Bm,
                         const float* __restrict__ bias, float* __restrict__ C,
                         int M, int N, int K) {
    __shared__ float As[BK][BM + 4];
    __shared__ float Bs[BK][BN];
    constexpr int TX = BN / TN;
    int tid = threadIdx.x;
    int tx = tid % TX, ty = tid / TX;
    int n0 = blockIdx.x * BN, m0 = blockIdx.y * BM;
    float acc[TM][TN];
    #pragma unroll
    for (int i = 0; i < TM; i++)
        #pragma unroll
        for (int j = 0; j < TN; j++) acc[i][j] = 0.f;
    for (int k0 = 0; k0 < K; k0 += BK) {
        #pragma unroll
        for (int e = 0; e < BM*BK/256; ++e) {
            int idx = tid + e*256;
            int mi = idx / BK, kk = idx % BK;
            int mm = m0 + mi, kg = k0 + kk;
            As[kk][mi] = (mm < M && kg < K) ? A[(size_t)mm*K + kg] : 0.f;
        }
        #pragma unroll
        for (int e = 0; e < BK*BN/256; ++e) {
            int idx = tid + e*256;
            int kk = idx / BN, nn = idx % BN;
            int kg = k0 + kk, ng = n0 + nn;
            Bs[kk][nn] = (kg < K && ng < N) ? Bm[(size_t)kg*N + ng] : 0.f;
        }
        __syncthreads();
        #pragma unroll
        for (int kk = 0; kk < BK; ++kk) {
            float ra[TM], rb[TN];
            #pragma unroll
            for (int i = 0; i < TM; i++) ra[i] = As[kk][ty*TM + i];
            #pragma unroll
            for (int j = 0; j < TN; j++) rb[j] = Bs[kk][tx*TN + j];
            #pragma unroll
            for (int i = 0; i < TM; i++)
                #pragma unroll
                for (int j = 0; j < TN; j++)
                    acc[i][j] = fmaf(ra[i], rb[j], acc[i][j]);
        }
        __syncthreads();
    }
    #pragma unroll
    for (int i = 0; i < TM; i++) {
        int mm = m0 + ty*TM + i;
        if (mm >= M) continue;
        #pragma unroll
        for (int j = 0; j < TN; j++) {
            int nn = n0 + tx*TN + j;
            if (nn < N) C[(size_t)mm*N + nn] = acc[i][j] + (bias ? bias[nn] : 0.f);
        }
    }
}

// ================= bf16 MFMA GEMM: C = act(A) @ B^T + bias ===================
// B stored transposed: Bt[n][k], k padded to 1024 with zeros.
// AMODE 0: A bf16 [M][1024]. AMODE 1: A fp32 [M][1000], selu applied. AMODE 2: A bf16, selu.
template<int AMODE>
__launch_bounds__(256)
__global__ void gemm_bf16(const void* __restrict__ Aptr, const unsigned short* __restrict__ Bt,
                          const float* __restrict__ bias, float* __restrict__ C, int ldc) {
    constexpr int BM = 64, BN = 128, BK = 64, KP = 72;  // +8 pad: bank-conflict-free
    __shared__ unsigned short As[BM * KP];
    __shared__ unsigned short Bs[BN * KP];
    int tid = threadIdx.x;
    int m0 = blockIdx.y * BM, n0 = blockIdx.x * BN;
    int lane = tid & 63, wid = tid >> 6;
    int wm = wid >> 1, wn = wid & 1;    // 2x2 waves, each 32x64 output
    f32x4 acc[2][4];
    #pragma unroll
    for (int i = 0; i < 2; i++)
        #pragma unroll
        for (int j = 0; j < 4; j++) acc[i][j] = (f32x4){0.f, 0.f, 0.f, 0.f};

    for (int k0 = 0; k0 < KP_G; k0 += BK) {
        // ---- stage A (2 chunks of 8 bf16 per thread) ----
        #pragma unroll
        for (int e = 0; e < 2; ++e) {
            int idx = tid + e*256;
            int row = idx >> 3, kc = idx & 7;
            int k = k0 + kc*8;
            int rg = m0 + row;
            bf16x8 v;
            if (AMODE == 1) {
                if (k < Hh) {  // 1000 % 8 == 0: chunk fully valid or fully pad
                    const float4* p = (const float4*)((const float*)Aptr + (size_t)rg*Hh + k);
                    float4 x = p[0], y = p[1];
                    v[0]=(short)f2bf(selu_f(x.x)); v[1]=(short)f2bf(selu_f(x.y));
                    v[2]=(short)f2bf(selu_f(x.z)); v[3]=(short)f2bf(selu_f(x.w));
                    v[4]=(short)f2bf(selu_f(y.x)); v[5]=(short)f2bf(selu_f(y.y));
                    v[6]=(short)f2bf(selu_f(y.z)); v[7]=(short)f2bf(selu_f(y.w));
                } else {
                    #pragma unroll
                    for (int j = 0; j < 8; j++) v[j] = 0;
                }
            } else {
                v = *(const bf16x8*)((const unsigned short*)Aptr + (size_t)rg*KP_G + k);
                if (AMODE == 2) {
                    #pragma unroll
                    for (int j = 0; j < 8; j++)
                        v[j] = (short)f2bf(selu_f(bf2f((unsigned short)v[j])));
                }
            }
            *(bf16x8*)(&As[row*KP + kc*8]) = v;
        }
        // ---- stage B (4 chunks) ----
        #pragma unroll
        for (int e = 0; e < 4; ++e) {
            int idx = tid + e*256;
            int row = idx >> 3, kc = idx & 7;
            bf16x8 v = *(const bf16x8*)(Bt + (size_t)(n0 + row)*KP_G + k0 + kc*8);
            *(bf16x8*)(&Bs[row*KP + kc*8]) = v;
        }
        __syncthreads();
        // ---- MFMA ----
        #pragma unroll
        for (int kk = 0; kk < 2; ++kk) {
            bf16x8 af[2], bfr[4];
            #pragma unroll
            for (int mi = 0; mi < 2; mi++)
                af[mi] = *(const bf16x8*)(&As[(wm*32 + mi*16 + (lane & 15))*KP + kk*32 + (lane >> 4)*8]);
            #pragma unroll
            for (int ni = 0; ni < 4; ni++)
                bfr[ni] = *(const bf16x8*)(&Bs[(wn*64 + ni*16 + (lane & 15))*KP + kk*32 + (lane >> 4)*8]);
            #pragma unroll
            for (int mi = 0; mi < 2; mi++)
                #pragma unroll
                for (int ni = 0; ni < 4; ni++)
                    acc[mi][ni] = __builtin_amdgcn_mfma_f32_16x16x32_bf16(af[mi], bfr[ni], acc[mi][ni], 0, 0, 0);
        }
        __syncthreads();
    }
    // ---- epilogue: D row = A row, col = B col; col=lane&15, row=(lane>>4)*4+r ----
    int cr = (lane >> 4) * 4, cc = lane & 15;
    #pragma unroll
    for (int mi = 0; mi < 2; mi++) {
        #pragma unroll
        for (int ni = 0; ni < 4; ni++) {
            int col = n0 + wn*64 + ni*16 + cc;
            float bv = bias ? bias[col] : 0.f;
            #pragma unroll
            for (int r = 0; r < 4; r++) {
                int row = m0 + wm*32 + mi*16 + cr + r;
                C[(size_t)row*ldc + col] = acc[mi][ni][r] + bv;
            }
        }
    }
}

// ================= GRU gates ================================================
__global__ void gates_kernel(const float* __restrict__ gi, const float* __restrict__ gh,
                             const float* __restrict__ h_prev, float* __restrict__ h_next,
                             unsigned short* __restrict__ hb) {
    int i = blockIdx.x*256 + threadIdx.x;  // 256*1024
    int b = i >> 10, j = i & 1023;
    if (j >= Hh) { hb[i] = 0; return; }
    const float* gib = gi + (size_t)b*3000;
    const float* ghb = gh + (size_t)b*3072;
    float r = 1.f/(1.f + expf(-(gib[j]        + ghb[j])));
    float z = 1.f/(1.f + expf(-(gib[1000 + j] + ghb[1000 + j])));
    float n = tanhf(gib[2000 + j] + r*ghb[2000 + j]);
    float h = (1.f - z)*n + z*h_prev[(size_t)b*Hh + j];
    h_next[(size_t)b*Hh + j] = h;
    hb[i] = f2bf(h);
}

// ================= per-(t,b) outputs ========================================
__global__ void output_kernel(const float* __restrict__ pe, const float* __restrict__ fu,
                              const float* __restrict__ encf, const float* __restrict__ b_fuse,
                              const float* __restrict__ W_copy, const float* __restrict__ b_copy,
                              float* __restrict__ out) {
    __shared__ float sf[100];
    __shared__ float swc[100];
    __shared__ float scp[101];
    __shared__ float spred[248];
    __shared__ float sred[256];
    int row = blockIdx.x;               // t*256 + b
    int b = row & 255;
    int tid = threadIdx.x, lane = tid & 63, wave = tid >> 6;
    if (tid < 100) { sf[tid] = fu[(size_t)row*128 + tid] + b_fuse[tid]; swc[tid] = W_copy[tid]; }
    if (tid < 248) spred[tid] = pe[(size_t)row*256 + tid];
    __syncthreads();
    if (tid == 0) scp[100] = spred[247];
    const float* efb = encf + (size_t)b*Ll*128;
    for (int l = wave; l < Ll; l += 4) {
        const float* ef = efb + (size_t)l*128;
        float p = selu_f(sf[lane] + ef[lane]) * swc[lane];
        if (lane < 36) p += selu_f(sf[lane+64] + ef[lane+64]) * swc[lane+64];
        for (int off = 32; off > 0; off >>= 1) p += __shfl_down(p, off);
        if (lane == 0) scp[l] = p + b_copy[0];
    }
    __syncthreads();
    float* ob = out + (size_t)row*OUTW;
    // log_softmax over pred (248)
    float m = (tid < 248) ? spred[tid] : -1e30f;
    sred[tid] = m; __syncthreads();
    for (int s = 128; s > 0; s >>= 1) { if (tid < s) sred[tid] = fmaxf(sred[tid], sred[tid+s]); __syncthreads(); }
    m = sred[0]; __syncthreads();
    float ps = (tid < 248) ? expf(spred[tid] - m) : 0.f;
    sred[tid] = ps; __syncthreads();
    for (int s = 128; s > 0; s >>= 1) { if (tid < s) sred[tid] += sred[tid+s]; __syncthreads(); }
    float lse = m + logf(sred[0]);
    __syncthreads();
    if (tid < 248) ob[tid] = spred[tid] - lse;
    // log_softmax over copy (101)
    m = (tid < 101) ? scp[tid] : -1e30f;
    sred[tid] = m; __syncthreads();
    for (int s = 128; s > 0; s >>= 1) { if (tid < s) sred[tid] = fmaxf(sred[tid], sred[tid+s]); __syncthreads(); }
    m = sred[0]; __syncthreads();
    ps = (tid < 101) ? expf(scp[tid] - m) : 0.f;
    sred[tid] = ps; __syncthreads();
    for (int s = 128; s > 0; s >>= 1) { if (tid < s) sred[tid] += sred[tid+s]; __syncthreads(); }
    lse = m + logf(sred[0]);
    __syncthreads();
    if (tid < 101) ob[248 + tid] = scp[tid] - lse;
}

// ============================================================================
extern "C" void kernel_launch(void* const* d_in, const int* in_sizes, int n_in,
                              void* d_out, int out_size, void* d_ws, size_t ws_size,
                              hipStream_t stream) {
    const float* emb    = (const float*)d_in[0];
    const float* enc    = (const float*)d_in[1];
    const float* conv   = (const float*)d_in[2];
    const float* h0     = (const float*)d_in[3];
    const float* W_attn = (const float*)d_in[4];
    const float* W_comb = (const float*)d_in[6];
    const float* b_comb = (const float*)d_in[7];
    const float* W_ih   = (const float*)d_in[8];
    const float* W_hh   = (const float*)d_in[9];
    const float* b_ih   = (const float*)d_in[10];
    const float* b_hh   = (const float*)d_in[11];
    const float* W_eos  = (const float*)d_in[12];
    const float* b_eos  = (const float*)d_in[13];
    const float* W_pred = (const float*)d_in[14];
    const float* b_pred = (const float*)d_in[15];
    const float* W_fuse = (const float*)d_in[16];
    const float* b_fuse = (const float*)d_in[17];
    const float* W_copy = (const float*)d_in[18];
    const float* b_copy = (const float*)d_in[19];
    float* out = (float*)d_out;

    char* p = (char*)d_ws;
    auto alloc = [&](size_t bytes) -> void* {
        void* r = (void*)p; p += (bytes + 255) & ~(size_t)255; return r;
    };
    float* s_enc  = (float*)alloc((size_t)Bb*Ll*4);
    float* s_conv = (float*)alloc((size_t)Bb*Rr*4);
    float* c_buf  = (float*)alloc((size_t)Bb*Hh*4);
    float* rc_buf = (float*)alloc((size_t)Bb*Hh*4);
    float* xc     = (float*)alloc((size_t)Bb*Ee*4);
    float* xrc    = (float*)alloc((size_t)Bb*Ee*4);
    float* x_all  = (float*)alloc((size_t)Tt*Bb*Ee*4);
    float* gi_all = (float*)alloc((size_t)Tt*Bb*3000*4);
    float* encf   = (float*)alloc((size_t)Bb*Ll*128*4);
    unsigned short* Wcat  = (unsigned short*)alloc((size_t)3072*KP_G*2);
    unsigned short* Whead = (unsigned short*)alloc((size_t)256*KP_G*2);
    unsigned short* Wft   = (unsigned short*)alloc((size_t)128*KP_G*2);
    unsigned short* Wfb   = (unsigned short*)alloc((size_t)128*KP_G*2);
    float* bcat    = (float*)alloc(3072*4);
    float* bias_pe = (float*)alloc(256*4);
    float* gh      = (float*)alloc((size_t)Bb*3072*4);
    float* h_a     = (float*)alloc((size_t)Bb*Hh*4);
    float* h_b     = (float*)alloc((size_t)Bb*Hh*4);
    unsigned short* h0b    = (unsigned short*)alloc((size_t)Bb*KP_G*2);
    unsigned short* hb_all = (unsigned short*)alloc((size_t)Tt*Bb*KP_G*2);
    float* pe = (float*)alloc((size_t)Tt*Bb*256*4);
    float* fu = (float*)alloc((size_t)Tt*Bb*128*4);

    // ---- attention (time-invariant) ----
    scores_kernel<<<(Bb*Ll + 15)/16, 256, 0, stream>>>(enc,  W_attn + Hh, s_enc,  Bb*Ll);
    scores_kernel<<<(Bb*Rr + 15)/16, 256, 0, stream>>>(conv, W_attn + Hh, s_conv, Bb*Rr);
    softmax_kernel<<<Bb, 256, 0, stream>>>(s_enc, Ll);
    softmax_kernel<<<Bb, 256, 0, stream>>>(s_conv, Rr);
    ctx_kernel<<<dim3(Bb, 4), 256, 0, stream>>>(enc,  s_enc,  c_buf,  Ll);
    ctx_kernel<<<dim3(Bb, 4), 256, 0, stream>>>(conv, s_conv, rc_buf, Rr);
    xcxrc_kernel<<<Bb, 128, 0, stream>>>(c_buf, rc_buf, W_comb, b_comb, xc, xrc);
    xall_kernel<<<Bb*Tt, 128, 0, stream>>>(emb, W_comb, xc, xrc, x_all);

    // ---- weight packing/transposition (bf16, [N][1024]) ----
    transpose_cvt<<<dim3(32, 96), dim3(32, 8), 0, stream>>>(W_hh,   3000, Hh, 3000, 0,    Wcat,  3072);
    transpose_cvt<<<dim3(32, 8),  dim3(32, 8), 0, stream>>>(W_pred, 247,  Hh, 247,  0,    Whead, 256);
    fill_eos_row<<<4, 256, 0, stream>>>(W_eos, Whead);
    transpose_cvt<<<dim3(32, 4),  dim3(32, 8), 0, stream>>>(W_fuse, 100,  Hh, 100,  0,    Wft,   128);
    transpose_cvt<<<dim3(32, 4),  dim3(32, 8), 0, stream>>>(W_fuse, 100,  Hh, 100,  1000, Wfb,   128);
    pack_biases<<<12, 256, 0, stream>>>(b_hh, b_pred, b_eos, bcat, bias_pe);

    // ---- batched precompute GEMMs ----
    gemm_f32<64,128,16,4,8><<<dim3(24, 60), 256, 0, stream>>>(x_all, W_ih, b_ih, gi_all, Tt*Bb, 3000, Ee);
    gemm_bf16<1><<<dim3(1, (Bb*Ll)/64), 256, 0, stream>>>(enc, Wfb, nullptr, encf, 128);  // selu(enc)@Wfuse_bot
    cvt_h0<<<Bb*KP_G/256, 256, 0, stream>>>(h0, h0b);

    // ---- serial GRU: gemm (h@W_hh) + gates only ----
    const unsigned short* hbprev = h0b;
    const float* hprev = h0;
    float* hcur = h_a;
    for (int t = 0; t < Tt; ++t) {
        gemm_bf16<0><<<dim3(24, 4), 256, 0, stream>>>(hbprev, Wcat, bcat, gh, 3072);
        gates_kernel<<<Bb*KP_G/256, 256, 0, stream>>>(gi_all + (size_t)t*Bb*3000, gh, hprev,
                                                      hcur, hb_all + (size_t)t*Bb*KP_G);
        hbprev = hb_all + (size_t)t*Bb*KP_G;
        hprev = hcur; hcur = (hcur == h_a) ? h_b : h_a;
    }

    // ---- batched heads over all (t,b) ----
    gemm_bf16<0><<<dim3(2, Tt*Bb/64), 256, 0, stream>>>(hb_all, Whead, bias_pe, pe, 256);
    gemm_bf16<2><<<dim3(1, Tt*Bb/64), 256, 0, stream>>>(hb_all, Wft, nullptr, fu, 128);
    output_kernel<<<Tt*Bb, 256, 0, stream>>>(pe, fu, encf, b_fuse, W_copy, b_copy, out);
}

// Round 3
// 614.157 us; speedup vs baseline: 8.4348x; 1.2517x over previous
//
#include <hip/hip_runtime.h>
#include <hip/hip_bf16.h>
#include <math.h>

#define SELU_ALPHA 1.6732632423543772f
#define SELU_SCALE 1.0507009873554805f

typedef __attribute__((ext_vector_type(8))) short bf16x8;
typedef __attribute__((ext_vector_type(4))) float f32x4;

__device__ __forceinline__ float selu_f(float x) {
    return x > 0.f ? SELU_SCALE * x : SELU_SCALE * SELU_ALPHA * (__expf(x) - 1.f);
}
__device__ __forceinline__ unsigned short f2bf(float f) {
    __hip_bfloat16 h = __float2bfloat16(f);
    return *(unsigned short*)&h;
}
__device__ __forceinline__ float bf2f(unsigned short u) {
    unsigned int x = ((unsigned int)u) << 16;
    float f; __builtin_memcpy(&f, &x, 4); return f;
}

constexpr int Bb = 256, Ll = 100, Hh = 1000, Ee = 100, Rr = 247, Tt = 15;
constexpr int KP_G = 1024;             // padded K for all bf16 GEMMs
constexpr int NCP = 3072;              // packed gate cols: 64 groups x 48 (r16|z16|n16)
constexpr int OUTW = Rr + 1 + Ll + 1;  // 349

// map packed col n' -> (part, j).  g=n'/48, rem=n'%48, part=rem/16, c=rem%16, j=g*16+c
__device__ __forceinline__ void unpack_col(int np, int& part, int& j) {
    int g = np / 48, rem = np % 48;
    part = rem >> 4;
    j = g * 16 + (rem & 15);
}

// ================= one-pass online-softmax attention ========================
// grid (B, nch); each block does rows [ch*chunk, min(N,(ch+1)*chunk)) online.
__global__ void attn_online(const float* __restrict__ mem, const float* __restrict__ Wb,
                            int Nmem, int chunk, float* __restrict__ part_ms,
                            float* __restrict__ part_ctx, int nch) {
    __shared__ float4 sWb[256];
    __shared__ float sred[2][8];
    int b = blockIdx.x, ch = blockIdx.y;
    int tid = threadIdx.x, lane = tid & 63, wv = tid >> 6;
    sWb[tid] = (tid < 250) ? ((const float4*)Wb)[tid] : (float4){0.f,0.f,0.f,0.f};
    __syncthreads();
    int l0 = ch * chunk, l1 = min(Nmem, l0 + chunk);
    float m = -1e30f, ssum = 0.f;
    float4 ctx = {0.f,0.f,0.f,0.f};
    const float* base = mem + (size_t)b * Nmem * 1000;
    float4 w = sWb[tid];
    int it = 0;
    for (int l = l0; l < l1; l += 2, ++it) {
        bool has1 = (l + 1 < l1);
        float4 v0 = {0,0,0,0}, v1 = {0,0,0,0};
        if (tid < 250) v0 = *(const float4*)(base + (size_t)l * 1000 + tid * 4);
        if (has1 && tid < 250) v1 = *(const float4*)(base + (size_t)(l+1) * 1000 + tid * 4);
        float p0 = v0.x*w.x + v0.y*w.y + v0.z*w.z + v0.w*w.w;
        float p1 = v1.x*w.x + v1.y*w.y + v1.z*w.z + v1.w*w.w;
        #pragma unroll
        for (int off = 32; off > 0; off >>= 1) {
            p0 += __shfl_down(p0, off);
            p1 += __shfl_down(p1, off);
        }
        int par = it & 1;
        if (lane == 0) { sred[par][wv*2] = p0; sred[par][wv*2+1] = p1; }
        __syncthreads();
        float s0 = sred[par][0] + sred[par][2] + sred[par][4] + sred[par][6];
        float s1 = has1 ? (sred[par][1] + sred[par][3] + sred[par][5] + sred[par][7]) : -1e30f;
        float mn = fmaxf(m, fmaxf(s0, s1));
        float sc = __expf(m - mn);
        float w0 = __expf(s0 - mn);
        float w1 = has1 ? __expf(s1 - mn) : 0.f;
        ssum = ssum * sc + w0 + w1;
        ctx.x = ctx.x*sc + w0*v0.x + w1*v1.x;
        ctx.y = ctx.y*sc + w0*v0.y + w1*v1.y;
        ctx.z = ctx.z*sc + w0*v0.z + w1*v1.z;
        ctx.w = ctx.w*sc + w0*v0.w + w1*v1.w;
        m = mn;
    }
    int pidx = b * nch + ch;
    if (tid == 0) { part_ms[pidx*2] = m; part_ms[pidx*2 + 1] = ssum; }
    if (tid < 250) *(float4*)(part_ctx + (size_t)pidx * 1000 + tid * 4) = ctx;
}

__global__ void attn_combine(const float* __restrict__ part_ms, const float* __restrict__ part_ctx,
                             float* __restrict__ ctx_out, int nch) {
    __shared__ float sm[4], ss[4];
    int b = blockIdx.x, tid = threadIdx.x;
    if (tid < nch) { sm[tid] = part_ms[(b*nch + tid)*2]; ss[tid] = part_ms[(b*nch + tid)*2 + 1]; }
    __syncthreads();
    float M = -1e30f;
    for (int c = 0; c < nch; ++c) M = fmaxf(M, sm[c]);
    float tot = 0.f;
    for (int c = 0; c < nch; ++c) tot += ss[c] * __expf(sm[c] - M);
    float inv = 1.f / tot;
    if (tid < 250) {
        float4 acc = {0,0,0,0};
        for (int c = 0; c < nch; ++c) {
            float wgt = __expf(sm[c] - M) * inv;
            float4 v = *(const float4*)(part_ctx + (size_t)(b*nch + c)*1000 + tid*4);
            acc.x += wgt*v.x; acc.y += wgt*v.y; acc.z += wgt*v.z; acc.w += wgt*v.w;
        }
        *(float4*)(ctx_out + (size_t)b*1000 + tid*4) = acc;
    }
}

// ================= small precompute kernels =================================
__global__ void xcxrc_kernel(const float* __restrict__ c, const float* __restrict__ rc,
                             const float* __restrict__ W_comb, const float* __restrict__ b_comb,
                             float* __restrict__ xc, float* __restrict__ xrc) {
    __shared__ float sc[1000];
    __shared__ float sr[1000];
    int b = blockIdx.x, tid = threadIdx.x;  // 128 threads
    for (int k = tid; k < Hh; k += 128) { sc[k] = c[(size_t)b*Hh+k]; sr[k] = rc[(size_t)b*Hh+k]; }
    __syncthreads();
    if (tid < Ee) {
        float a0 = 0.f, a1 = 0.f;
        for (int k = 0; k < Hh; ++k) {
            float w = W_comb[(size_t)(Ee + k)*Ee + tid];
            a0 += sc[k]*w; a1 += sr[k]*w;
        }
        xc [(size_t)b*Ee + tid] = a0 + b_comb[tid];
        xrc[(size_t)b*Ee + tid] = a1 + b_comb[tid];
    }
}

__global__ void xall_kernel(const float* __restrict__ emb, const float* __restrict__ W_comb,
                            const float* __restrict__ xc, const float* __restrict__ xrc,
                            float* __restrict__ x_all) {
    __shared__ float se[100];
    int bt = blockIdx.x; int b = bt / Tt, t = bt % Tt;
    int tid = threadIdx.x;  // 128
    if (tid < Ee) se[tid] = emb[(size_t)(b*Tt + t)*Ee + tid];
    __syncthreads();
    if (tid < Ee) {
        float a = 0.f;
        for (int k = 0; k < Ee; ++k) a += se[k] * W_comb[(size_t)k*Ee + tid];
        const float* xs = (t % 3 == 0) ? xrc : xc;
        x_all[((size_t)t*Bb + b)*Ee + tid] = a + xs[(size_t)b*Ee + tid];
    }
}

// transpose+convert: dst[n][k] (ld 1024) = bf16(src[(row0+k)*srcLd + n]), zero-padded
__global__ void transpose_cvt(const float* __restrict__ src, int srcLd, int kValid, int nValid,
                              int row0, unsigned short* __restrict__ dst, int nRows) {
    __shared__ float tile[32][33];
    int k0 = blockIdx.x * 32, n0 = blockIdx.y * 32;
    int tx = threadIdx.x, ty = threadIdx.y;  // 32 x 8
    for (int i = ty; i < 32; i += 8) {
        int k = k0 + i, n = n0 + tx;
        tile[i][tx] = (k < kValid && n < nValid) ? src[(size_t)(row0 + k)*srcLd + n] : 0.f;
    }
    __syncthreads();
    for (int i = ty; i < 32; i += 8) {
        int n = n0 + i, k = k0 + tx;
        if (n < nRows) dst[(size_t)n*KP_G + k] = f2bf(tile[tx][i]);
    }
}

// W_hh -> packed-gates, transposed bf16: Wp[n'][k]
__global__ void pack_whh(const float* __restrict__ W_hh, unsigned short* __restrict__ Wp) {
    __shared__ float tile[32][33];
    int k0 = blockIdx.x * 32, n0 = blockIdx.y * 32;
    int tx = threadIdx.x, ty = threadIdx.y;  // 32 x 8
    for (int i = ty; i < 32; i += 8) {
        int k = k0 + i, np = n0 + tx;
        int part, j; unpack_col(np, part, j);
        tile[i][tx] = (k < Hh && j < Hh) ? W_hh[(size_t)k*3000 + part*1000 + j] : 0.f;
    }
    __syncthreads();
    for (int i = ty; i < 32; i += 8) {
        int np = n0 + i, k = k0 + tx;
        Wp[(size_t)np*KP_G + k] = f2bf(tile[tx][i]);
    }
}

// W_ih -> packed cols fp32 [100][3072]
__global__ void pack_wih(const float* __restrict__ W_ih, float* __restrict__ Wihp) {
    int idx = blockIdx.x*256 + threadIdx.x;
    if (idx >= Ee * NCP) return;
    int k = idx / NCP, np = idx % NCP;
    int part, j; unpack_col(np, part, j);
    Wihp[idx] = (j < Hh) ? W_ih[(size_t)k*3000 + part*1000 + j] : 0.f;
}

__global__ void fill_eos_row(const float* __restrict__ W_eos, unsigned short* __restrict__ Whead) {
    int k = blockIdx.x*256 + threadIdx.x;
    if (k < KP_G) Whead[(size_t)247*KP_G + k] = f2bf(k < Hh ? W_eos[k] : 0.f);
}

__global__ void pack_biases(const float* __restrict__ b_hh, const float* __restrict__ b_ih,
                            const float* __restrict__ b_pred, const float* __restrict__ b_eos,
                            float* __restrict__ bhhp, float* __restrict__ bihp,
                            float* __restrict__ bias_pe) {
    int i = blockIdx.x*256 + threadIdx.x;
    if (i < NCP) {
        int part, j; unpack_col(i, part, j);
        bhhp[i] = (j < Hh) ? b_hh[part*1000 + j] : 0.f;
        bihp[i] = (j < Hh) ? b_ih[part*1000 + j] : 0.f;
    }
    if (i < 256) bias_pe[i] = (i < 247) ? b_pred[i] : (i == 247 ? b_eos[0] : 0.f);
}

__global__ void cvt_h0(const float* __restrict__ h0, unsigned short* __restrict__ h0b,
                       float* __restrict__ h0f) {
    int i = blockIdx.x*256 + threadIdx.x;  // 256*1024
    int b = i >> 10, j = i & 1023;
    float v = (j < Hh) ? h0[(size_t)b*Hh + j] : 0.f;
    h0b[i] = f2bf(v);
    h0f[i] = v;
}

// ================= fp32 GEMM (gi_all: K=100) =================================
template<int BM, int BN, int BK, int TM, int TN>
__launch_bounds__(256)
__global__ void gemm_f32(const float* __restrict__ A, const float* __restrict__ Bm,
                         const float* __restrict__ bias, float* __restrict__ C,
                         int M, int N, int K) {
    __shared__ float As[BK][BM + 4];
    __shared__ float Bs[BK][BN];
    constexpr int TX = BN / TN;
    int tid = threadIdx.x;
    int tx = tid % TX, ty = tid / TX;
    int n0 = blockIdx.x * BN, m0 = blockIdx.y * BM;
    float acc[TM][TN];
    #pragma unroll
    for (int i = 0; i < TM; i++)
        #pragma unroll
        for (int j = 0; j < TN; j++) acc[i][j] = 0.f;
    for (int k0 = 0; k0 < K; k0 += BK) {
        #pragma unroll
        for (int e = 0; e < BM*BK/256; ++e) {
            int idx = tid + e*256;
            int mi = idx / BK, kk = idx % BK;
            int mm = m0 + mi, kg = k0 + kk;
            As[kk][mi] = (mm < M && kg < K) ? A[(size_t)mm*K + kg] : 0.f;
        }
        #pragma unroll
        for (int e = 0; e < BK*BN/256; ++e) {
            int idx = tid + e*256;
            int kk = idx / BN, nn = idx % BN;
            int kg = k0 + kk, ng = n0 + nn;
            Bs[kk][nn] = (kg < K && ng < N) ? Bm[(size_t)kg*N + ng] : 0.f;
        }
        __syncthreads();
        #pragma unroll
        for (int kk = 0; kk < BK; ++kk) {
            float ra[TM], rb[TN];
            #pragma unroll
            for (int i = 0; i < TM; i++) ra[i] = As[kk][ty*TM + i];
            #pragma unroll
            for (int j = 0; j < TN; j++) rb[j] = Bs[kk][tx*TN + j];
            #pragma unroll
            for (int i = 0; i < TM; i++)
                #pragma unroll
                for (int j = 0; j < TN; j++)
                    acc[i][j] = fmaf(ra[i], rb[j], acc[i][j]);
        }
        __syncthreads();
    }
    #pragma unroll
    for (int i = 0; i < TM; i++) {
        int mm = m0 + ty*TM + i;
        if (mm >= M) continue;
        #pragma unroll
        for (int j = 0; j < TN; j++) {
            int nn = n0 + tx*TN + j;
            if (nn < N) C[(size_t)mm*N + nn] = acc[i][j] + (bias ? bias[nn] : 0.f);
        }
    }
}

// ================= bf16 MFMA GEMM (heads / encf) =============================
// B stored transposed: Bt[n][k], k padded to 1024.
// AMODE 0: A bf16 [M][1024]. AMODE 1: A fp32 [M][1000], selu applied. AMODE 2: A bf16, selu.
template<int AMODE>
__launch_bounds__(256)
__global__ void gemm_bf16(const void* __restrict__ Aptr, const unsigned short* __restrict__ Bt,
                          const float* __restrict__ bias, float* __restrict__ C, int ldc) {
    constexpr int BM = 64, BN = 128, BK = 64, KP = 72;
    __shared__ unsigned short As[BM * KP];
    __shared__ unsigned short Bs[BN * KP];
    int tid = threadIdx.x;
    int m0 = blockIdx.y * BM, n0 = blockIdx.x * BN;
    int lane = tid & 63, wid = tid >> 6;
    int wm = wid >> 1, wn = wid & 1;
    f32x4 acc[2][4];
    #pragma unroll
    for (int i = 0; i < 2; i++)
        #pragma unroll
        for (int j = 0; j < 4; j++) acc[i][j] = (f32x4){0.f, 0.f, 0.f, 0.f};

    for (int k0 = 0; k0 < KP_G; k0 += BK) {
        #pragma unroll
        for (int e = 0; e < 2; ++e) {
            int idx = tid + e*256;
            int row = idx >> 3, kc = idx & 7;
            int k = k0 + kc*8;
            int rg = m0 + row;
            bf16x8 v;
            if (AMODE == 1) {
                if (k < Hh) {
                    const float4* p = (const float4*)((const float*)Aptr + (size_t)rg*Hh + k);
                    float4 x = p[0], y = p[1];
                    v[0]=(short)f2bf(selu_f(x.x)); v[1]=(short)f2bf(selu_f(x.y));
                    v[2]=(short)f2bf(selu_f(x.z)); v[3]=(short)f2bf(selu_f(x.w));
                    v[4]=(short)f2bf(selu_f(y.x)); v[5]=(short)f2bf(selu_f(y.y));
                    v[6]=(short)f2bf(selu_f(y.z)); v[7]=(short)f2bf(selu_f(y.w));
                } else {
                    #pragma unroll
                    for (int j = 0; j < 8; j++) v[j] = 0;
                }
            } else {
                v = *(const bf16x8*)((const unsigned short*)Aptr + (size_t)rg*KP_G + k);
                if (AMODE == 2) {
                    #pragma unroll
                    for (int j = 0; j < 8; j++)
                        v[j] = (short)f2bf(selu_f(bf2f((unsigned short)v[j])));
                }
            }
            *(bf16x8*)(&As[row*KP + kc*8]) = v;
        }
        #pragma unroll
        for (int e = 0; e < 4; ++e) {
            int idx = tid + e*256;
            int row = idx >> 3, kc = idx & 7;
            bf16x8 v = *(const bf16x8*)(Bt + (size_t)(n0 + row)*KP_G + k0 + kc*8);
            *(bf16x8*)(&Bs[row*KP + kc*8]) = v;
        }
        __syncthreads();
        #pragma unroll
        for (int kk = 0; kk < 2; ++kk) {
            bf16x8 af[2], bfr[4];
            #pragma unroll
            for (int mi = 0; mi < 2; mi++)
                af[mi] = *(const bf16x8*)(&As[(wm*32 + mi*16 + (lane & 15))*KP + kk*32 + (lane >> 4)*8]);
            #pragma unroll
            for (int ni = 0; ni < 4; ni++)
                bfr[ni] = *(const bf16x8*)(&Bs[(wn*64 + ni*16 + (lane & 15))*KP + kk*32 + (lane >> 4)*8]);
            #pragma unroll
            for (int mi = 0; mi < 2; mi++)
                #pragma unroll
                for (int ni = 0; ni < 4; ni++)
                    acc[mi][ni] = __builtin_amdgcn_mfma_f32_16x16x32_bf16(af[mi], bfr[ni], acc[mi][ni], 0, 0, 0);
        }
        __syncthreads();
    }
    int cr = (lane >> 4) * 4, cc = lane & 15;
    #pragma unroll
    for (int mi = 0; mi < 2; mi++) {
        #pragma unroll
        for (int ni = 0; ni < 4; ni++) {
            int col = n0 + wn*64 + ni*16 + cc;
            float bv = bias ? bias[col] : 0.f;
            #pragma unroll
            for (int r = 0; r < 4; r++) {
                int row = m0 + wm*32 + mi*16 + cr + r;
                C[(size_t)row*ldc + col] = acc[mi][ni][r] + bv;
            }
        }
    }
}

// ================= fused GRU step: h@Whh (packed) + gates in epilogue ========
// grid (32, 8): n-tiles of 96 (2 gate-groups), m-tiles of 32. 4 waves: wm x wn.
__launch_bounds__(256)
__global__ void gru_step(const unsigned short* __restrict__ hbA, const unsigned short* __restrict__ Wp,
                         const float* __restrict__ bhhp, const float* __restrict__ gi,
                         const float* __restrict__ hprevf, float* __restrict__ hnextf,
                         unsigned short* __restrict__ hb_out) {
    constexpr int BK = 64, KP = 72;
    __shared__ unsigned short As[32 * KP];
    __shared__ unsigned short Bs[96 * KP];
    int tid = threadIdx.x, lane = tid & 63, wid = tid >> 6;
    int wm = wid >> 1, wn = wid & 1;
    int n0 = blockIdx.x * 96, m0 = blockIdx.y * 32;
    f32x4 acc[3];
    #pragma unroll
    for (int f = 0; f < 3; f++) acc[f] = (f32x4){0.f,0.f,0.f,0.f};

    for (int k0 = 0; k0 < KP_G; k0 += BK) {
        {   // stage A: 32 rows x 64 k = 256 chunks of 8
            int row = tid >> 3, kc = tid & 7;
            *(bf16x8*)(&As[row*KP + kc*8]) =
                *(const bf16x8*)(hbA + (size_t)(m0 + row)*KP_G + k0 + kc*8);
        }
        #pragma unroll
        for (int e = 0; e < 3; ++e) {   // stage B: 96 x 64 = 768 chunks
            int idx = tid + e*256;
            int row = idx >> 3, kc = idx & 7;
            *(bf16x8*)(&Bs[row*KP + kc*8]) =
                *(const bf16x8*)(Wp + (size_t)(n0 + row)*KP_G + k0 + kc*8);
        }
        __syncthreads();
        #pragma unroll
        for (int kk = 0; kk < 2; ++kk) {
            bf16x8 af = *(const bf16x8*)(&As[(wm*16 + (lane & 15))*KP + kk*32 + (lane >> 4)*8]);
            #pragma unroll
            for (int f = 0; f < 3; f++) {
                bf16x8 bf = *(const bf16x8*)(&Bs[(wn*48 + f*16 + (lane & 15))*KP + kk*32 + (lane >> 4)*8]);
                acc[f] = __builtin_amdgcn_mfma_f32_16x16x32_bf16(af, bf, acc[f], 0, 0, 0);
            }
        }
        __syncthreads();
    }
    // epilogue: gates. lane holds r/z/n for j = g*16 + c, rows (lane>>4)*4 + r.
    int c = lane & 15, r0 = (lane >> 4) * 4;
    int g = n0 / 48 + wn;
    int j = g * 16 + c;
    float br = bhhp[g*48 + c], bz = bhhp[g*48 + 16 + c], bn_ = bhhp[g*48 + 32 + c];
    #pragma unroll
    for (int r = 0; r < 4; r++) {
        int row = m0 + wm*16 + r0 + r;
        const float* girow = gi + (size_t)row*NCP + g*48;
        float gh_r = acc[0][r] + br;
        float gh_z = acc[1][r] + bz;
        float gh_n = acc[2][r] + bn_;
        float rr = 1.f/(1.f + expf(-(girow[c] + gh_r)));
        float zz = 1.f/(1.f + expf(-(girow[16 + c] + gh_z)));
        float nn = tanhf(girow[32 + c] + rr * gh_n);
        float hp = hprevf[(size_t)row*KP_G + j];
        float h = (1.f - zz)*nn + zz*hp;
        hnextf[(size_t)row*KP_G + j] = h;
        hb_out[(size_t)row*KP_G + j] = f2bf(h);
    }
}

// ================= per-(t,b) outputs ========================================
__global__ void output_kernel(const float* __restrict__ pe, const float* __restrict__ fu,
                              const float* __restrict__ encf, const float* __restrict__ b_fuse,
                              const float* __restrict__ W_copy, const float* __restrict__ b_copy,
                              float* __restrict__ out) {
    __shared__ float sf[100];
    __shared__ float swc[100];
    __shared__ float scp[101];
    __shared__ float spred[248];
    __shared__ float sred[256];
    int row = blockIdx.x;               // t*256 + b
    int b = row & 255;
    int tid = threadIdx.x, lane = tid & 63, wave = tid >> 6;
    if (tid < 100) { sf[tid] = fu[(size_t)row*128 + tid] + b_fuse[tid]; swc[tid] = W_copy[tid]; }
    if (tid < 248) spred[tid] = pe[(size_t)row*256 + tid];
    __syncthreads();
    if (tid == 0) scp[100] = spred[247];
    const float* efb = encf + (size_t)b*Ll*128;
    for (int l = wave; l < Ll; l += 4) {
        const float* ef = efb + (size_t)l*128;
        float p = selu_f(sf[lane] + ef[lane]) * swc[lane];
        if (lane < 36) p += selu_f(sf[lane+64] + ef[lane+64]) * swc[lane+64];
        for (int off = 32; off > 0; off >>= 1) p += __shfl_down(p, off);
        if (lane == 0) scp[l] = p + b_copy[0];
    }
    __syncthreads();
    float* ob = out + (size_t)row*OUTW;
    float m = (tid < 248) ? spred[tid] : -1e30f;
    sred[tid] = m; __syncthreads();
    for (int s = 128; s > 0; s >>= 1) { if (tid < s) sred[tid] = fmaxf(sred[tid], sred[tid+s]); __syncthreads(); }
    m = sred[0]; __syncthreads();
    float ps = (tid < 248) ? expf(spred[tid] - m) : 0.f;
    sred[tid] = ps; __syncthreads();
    for (int s = 128; s > 0; s >>= 1) { if (tid < s) sred[tid] += sred[tid+s]; __syncthreads(); }
    float lse = m + logf(sred[0]);
    __syncthreads();
    if (tid < 248) ob[tid] = spred[tid] - lse;
    m = (tid < 101) ? scp[tid] : -1e30f;
    sred[tid] = m; __syncthreads();
    for (int s = 128; s > 0; s >>= 1) { if (tid < s) sred[tid] = fmaxf(sred[tid], sred[tid+s]); __syncthreads(); }
    m = sred[0]; __syncthreads();
    ps = (tid < 101) ? expf(scp[tid] - m) : 0.f;
    sred[tid] = ps; __syncthreads();
    for (int s = 128; s > 0; s >>= 1) { if (tid < s) sred[tid] += sred[tid+s]; __syncthreads(); }
    lse = m + logf(sred[0]);
    __syncthreads();
    if (tid < 101) ob[248 + tid] = scp[tid] - lse;
}

// ============================================================================
extern "C" void kernel_launch(void* const* d_in, const int* in_sizes, int n_in,
                              void* d_out, int out_size, void* d_ws, size_t ws_size,
                              hipStream_t stream) {
    const float* emb    = (const float*)d_in[0];
    const float* enc    = (const float*)d_in[1];
    const float* conv   = (const float*)d_in[2];
    const float* h0     = (const float*)d_in[3];
    const float* W_attn = (const float*)d_in[4];
    const float* W_comb = (const float*)d_in[6];
    const float* b_comb = (const float*)d_in[7];
    const float* W_ih   = (const float*)d_in[8];
    const float* W_hh   = (const float*)d_in[9];
    const float* b_ih   = (const float*)d_in[10];
    const float* b_hh   = (const float*)d_in[11];
    const float* W_eos  = (const float*)d_in[12];
    const float* b_eos  = (const float*)d_in[13];
    const float* W_pred = (const float*)d_in[14];
    const float* b_pred = (const float*)d_in[15];
    const float* W_fuse = (const float*)d_in[16];
    const float* b_fuse = (const float*)d_in[17];
    const float* W_copy = (const float*)d_in[18];
    const float* b_copy = (const float*)d_in[19];
    float* out = (float*)d_out;

    char* p = (char*)d_ws;
    auto alloc = [&](size_t bytes) -> void* {
        void* r = (void*)p; p += (bytes + 255) & ~(size_t)255; return r;
    };
    float* pm_enc   = (float*)alloc((size_t)Bb*2*2*4);
    float* pm_conv  = (float*)alloc((size_t)Bb*4*2*4);
    float* pc_enc   = (float*)alloc((size_t)Bb*2*1000*4);
    float* pc_conv  = (float*)alloc((size_t)Bb*4*1000*4);
    float* c_buf  = (float*)alloc((size_t)Bb*Hh*4);
    float* rc_buf = (float*)alloc((size_t)Bb*Hh*4);
    float* xc     = (float*)alloc((size_t)Bb*Ee*4);
    float* xrc    = (float*)alloc((size_t)Bb*Ee*4);
    float* x_all  = (float*)alloc((size_t)Tt*Bb*Ee*4);
    float* gi_all = (float*)alloc((size_t)Tt*Bb*NCP*4);
    float* encf   = (float*)alloc((size_t)Bb*Ll*128*4);
    unsigned short* Wp    = (unsigned short*)alloc((size_t)NCP*KP_G*2);
    unsigned short* Whead = (unsigned short*)alloc((size_t)256*KP_G*2);
    unsigned short* Wft   = (unsigned short*)alloc((size_t)128*KP_G*2);
    unsigned short* Wfb   = (unsigned short*)alloc((size_t)128*KP_G*2);
    float* Wihp    = (float*)alloc((size_t)Ee*NCP*4);
    float* bhhp    = (float*)alloc(NCP*4);
    float* bihp    = (float*)alloc(NCP*4);
    float* bias_pe = (float*)alloc(256*4);
    float* h_f[2];
    h_f[0] = (float*)alloc((size_t)Bb*KP_G*4);
    h_f[1] = (float*)alloc((size_t)Bb*KP_G*4);
    float* h0f = (float*)alloc((size_t)Bb*KP_G*4);
    unsigned short* h0b    = (unsigned short*)alloc((size_t)Bb*KP_G*2);
    unsigned short* hb_all = (unsigned short*)alloc((size_t)Tt*Bb*KP_G*2);
    float* pe = (float*)alloc((size_t)Tt*Bb*256*4);
    float* fu = (float*)alloc((size_t)Tt*Bb*128*4);

    // ---- attention (time-invariant; one pass, online softmax) ----
    attn_online<<<dim3(Bb, 2), 256, 0, stream>>>(enc,  W_attn + Hh, Ll, 50, pm_enc,  pc_enc,  2);
    attn_online<<<dim3(Bb, 4), 256, 0, stream>>>(conv, W_attn + Hh, Rr, 62, pm_conv, pc_conv, 4);
    attn_combine<<<Bb, 256, 0, stream>>>(pm_enc,  pc_enc,  c_buf,  2);
    attn_combine<<<Bb, 256, 0, stream>>>(pm_conv, pc_conv, rc_buf, 4);
    xcxrc_kernel<<<Bb, 128, 0, stream>>>(c_buf, rc_buf, W_comb, b_comb, xc, xrc);
    xall_kernel<<<Bb*Tt, 128, 0, stream>>>(emb, W_comb, xc, xrc, x_all);

    // ---- weight packing ----
    pack_whh<<<dim3(32, 96), dim3(32, 8), 0, stream>>>(W_hh, Wp);
    pack_wih<<<(Ee*NCP + 255)/256, 256, 0, stream>>>(W_ih, Wihp);
    transpose_cvt<<<dim3(32, 8), dim3(32, 8), 0, stream>>>(W_pred, 247, Hh, 247, 0,    Whead, 256);
    fill_eos_row<<<4, 256, 0, stream>>>(W_eos, Whead);
    transpose_cvt<<<dim3(32, 4), dim3(32, 8), 0, stream>>>(W_fuse, 100, Hh, 100, 0,    Wft, 128);
    transpose_cvt<<<dim3(32, 4), dim3(32, 8), 0, stream>>>(W_fuse, 100, Hh, 100, 1000, Wfb, 128);
    pack_biases<<<12, 256, 0, stream>>>(b_hh, b_ih, b_pred, b_eos, bhhp, bihp, bias_pe);
    cvt_h0<<<Bb*KP_G/256, 256, 0, stream>>>(h0, h0b, h0f);

    // ---- batched precompute GEMMs ----
    gemm_f32<64,128,16,4,8><<<dim3(NCP/128, Tt*Bb/64), 256, 0, stream>>>(x_all, Wihp, bihp, gi_all, Tt*Bb, NCP, Ee);
    gemm_bf16<1><<<dim3(1, (Bb*Ll)/64), 256, 0, stream>>>(enc, Wfb, nullptr, encf, 128);

    // ---- serial GRU: one fused kernel per step ----
    const unsigned short* hbprev = h0b;
    const float* hprev = h0f;
    for (int t = 0; t < Tt; ++t) {
        float* hnext = h_f[t & 1];
        unsigned short* hbnext = hb_all + (size_t)t*Bb*KP_G;
        gru_step<<<dim3(32, 8), 256, 0, stream>>>(hbprev, Wp, bhhp,
                                                  gi_all + (size_t)t*Bb*NCP,
                                                  hprev, hnext, hbnext);
        hbprev = hbnext; hprev = hnext;
    }

    // ---- batched heads over all (t,b) ----
    gemm_bf16<0><<<dim3(2, Tt*Bb/64), 256, 0, stream>>>(hb_all, Whead, bias_pe, pe, 256);
    gemm_bf16<2><<<dim3(1, Tt*Bb/64), 256, 0, stream>>>(hb_all, Wft, nullptr, fu, 128);
    output_kernel<<<Tt*Bb, 256, 0, stream>>>(pe, fu, encf, b_fuse, W_copy, b_copy, out);
}